// Round 1
// baseline (308.992 us; speedup 1.0000x reference)
//
#include <hip/hip_runtime.h>

typedef _Float16 f16;
typedef _Float16 f16x4 __attribute__((ext_vector_type(4)));
typedef _Float16 f16x8 __attribute__((ext_vector_type(8)));
typedef float    fx4   __attribute__((ext_vector_type(4)));

#define MODE_PROJ   0
#define MODE_SCORES 1
#define MODE_PV     2

constexpr int Bsz = 4;
constexpr int S   = 2048;
constexpr int DK  = 1024;
constexpr int BM = 128, BN = 256, BK = 64;
constexpr long SD   = (long)S * DK;          // 2M elems
constexpr long SS   = (long)S * S;           // 4M elems
constexpr long BIGN = (long)Bsz * S * DK;    // 8M elems

// async global->LDS, 16B per lane; LDS dest wave-uniform (HW adds lane*16)
__device__ __forceinline__ void glds16(const f16* g, f16* l) {
    __builtin_amdgcn_global_load_lds(
        (const __attribute__((address_space(1))) void*)g,
        (__attribute__((address_space(3))) void*)l, 16, 0, 0);
}

// In-place fp32 -> fp16 conversion, pair-packed:
//   f16 idx = (r>>1)*4096 + (r&1)*1024 + c   (region stride 4096 f16 = 8192 B)
__global__ __launch_bounds__(256)
void convert_kernel(const float* q, const float* k, const float* v,
                    const float* wq, const float* wk, const float* wv)
{
    int bx = blockIdx.x;
    const float* src;
    int blk;
    if (bx < 12288) {
        int t = bx >> 12; blk = bx & 4095;
        src = (t == 0) ? q : (t == 1) ? k : v;
    } else {
        int u = bx - 12288;
        int t = u >> 9; blk = u & 511;
        src = (t == 0) ? wq : (t == 1) ? wk : wv;
    }
    size_t off = (size_t)blk * 2048 + (size_t)threadIdx.x * 8;
    float4 f0 = *(const float4*)(src + off);
    float4 f1 = *(const float4*)(src + off + 4);
    __syncthreads();
    f16x8 h = {(f16)f0.x, (f16)f0.y, (f16)f0.z, (f16)f0.w,
               (f16)f1.x, (f16)f1.y, (f16)f1.z, (f16)f1.w};
    *(f16x8*)((char*)src + (size_t)blk * 8192 + (size_t)threadIdx.x * 16) = h;
}

__device__ __forceinline__ size_t pp(int r, int c) {
    return ((size_t)(r >> 1) << 12) + ((r & 1) << 10) + c;
}

// NT GEMM, fp16. 128x256x64 tiles, 512 threads (8 waves, 2x4), double-buffered
// LDS, 4-phase schedule per K-tile:
//   ph0: ds_read A-half0 + B-half0 frags, issue FULL next-tile glds into buf^1,
//        s_barrier, MFMA quadrant (0,0), s_barrier
//   ph1: ds_read B-half1, bar, MFMA (0,1), bar
//   ph2: ds_read A-half1, bar, MFMA (1,1), bar
//   ph3: MFMA (1,0) (frags resident), __syncthreads (drains vmcnt after ~3
//        phases of cover -> near-free), swap buffers.
// Race-free by construction: in-flight glds only ever target the non-compute
// buffer; raw s_barrier between phases keeps loads in flight (no drain).
template<int MODE>
__global__ __launch_bounds__(512, 2)
void gemm_kernel(const f16* A0, const f16* A1, const f16* A2,
                 const f16* B0, const f16* B1, const f16* B2,
                 void* O0, void* O1, float* rowsum,
                 int lda, int ldb, int K, int ldo)
{
    __shared__ __attribute__((aligned(16))) f16 lA[2][BM * BK];   // 32 KB
    __shared__ __attribute__((aligned(16))) f16 lB[2][BN * BK];   // 64 KB

    const int tid = threadIdx.x;
    const int id  = blockIdx.x;
    const int z   = blockIdx.y;
    int row0, col0;
    if constexpr (MODE == MODE_PROJ) { row0 = (id & 63) * BM; col0 = (id >> 6) * BN; }
    else                             { row0 = (id & 15) * BM; col0 = (id >> 4) * BN; }

    const int lane = tid & 63;
    const int quad = lane >> 4;
    const int cn   = lane & 15;
    const int w    = tid >> 6;   // 0..7
    const int wm   = w >> 2;     // 0..1  (64 rows each)
    const int wn   = w & 3;      // 0..3  (64 cols each)

    const f16 *Ap, *Bp;
    if constexpr (MODE == MODE_PROJ) {
        Ap = (z == 0) ? A0 : (z == 1) ? A1 : A2;
        Bp = (z == 0) ? B0 : (z == 1) ? B1 : B2;
    } else if constexpr (MODE == MODE_SCORES) {
        Ap = A0 + (long)z * SD;  Bp = B0 + (long)z * SD;
        rowsum += (long)z * S;
    } else {
        Ap = A0 + (long)z * SS;  Bp = B0 + (long)z * SD;
        rowsum += (long)z * S;
    }

    fx4 acc[4][4];
    #pragma unroll
    for (int mt = 0; mt < 4; ++mt)
        #pragma unroll
        for (int nt = 0; nt < 4; ++nt)
            acc[mt][nt] = (fx4){0.f, 0.f, 0.f, 0.f};

    // staging lane map: 8 rows x 8 chunks of 16B; fetch XOR-permuted chunk so
    // LDS physical chunk (lane&7) holds global chunk (lane&7)^(row&7)
    const int lr8 = lane >> 3;            // 0..7 row within 8-row group
    const int swc = (lane & 7) ^ lr8;     // swizzled global chunk
    const int lcS = swc << 3;             // f16 col within BK

    f16x8 af[4];   // current A half: [m(2)][kh(2)]
    f16x8 bf[8];   // full B tile:   [nt(4)][kh(2)]

#define STAGE(BUF, K0) do {                                                          \
    _Pragma("unroll")                                                                \
    for (int i_ = 0; i_ < 2; ++i_) {                                                 \
        int rb_ = w * 16 + i_ * 8;                                                   \
        if constexpr (MODE == MODE_PROJ)                                             \
            glds16(Ap + pp(row0 + rb_ + lr8, (K0) + lcS), &lA[BUF][rb_ * BK]);       \
        else                                                                         \
            glds16(Ap + (size_t)(row0 + rb_ + lr8) * lda + (K0) + lcS,               \
                   &lA[BUF][rb_ * BK]);                                              \
    }                                                                                \
    _Pragma("unroll")                                                                \
    for (int i_ = 0; i_ < 4; ++i_) {                                                 \
        int rb_ = w * 32 + i_ * 8;                                                   \
        if constexpr (MODE == MODE_PROJ)                                             \
            glds16(Bp + pp(col0 + rb_ + lr8, (K0) + lcS), &lB[BUF][rb_ * BK]);       \
        else                                                                         \
            glds16(Bp + (size_t)(col0 + rb_ + lr8) * ldb + (K0) + lcS,               \
                   &lB[BUF][rb_ * BK]);                                              \
    }                                                                                \
} while (0)

#define LDA_FRAGS(BUF, MH) do {                                                      \
    _Pragma("unroll")                                                                \
    for (int m_ = 0; m_ < 2; ++m_)                                                   \
        _Pragma("unroll")                                                            \
        for (int kk_ = 0; kk_ < 2; ++kk_) {                                          \
            int r_  = wm * 64 + ((MH) * 2 + m_) * 16 + cn;                           \
            int ch_ = ((kk_ << 2) | quad) ^ (r_ & 7);                                \
            af[m_ * 2 + kk_] = *(const f16x8*)&lA[BUF][r_ * BK + ch_ * 8];           \
        }                                                                            \
} while (0)

#define LDB_FRAGS(BUF, NH) do {                                                      \
    _Pragma("unroll")                                                                \
    for (int n_ = 0; n_ < 2; ++n_)                                                   \
        _Pragma("unroll")                                                            \
        for (int kk_ = 0; kk_ < 2; ++kk_) {                                          \
            int nt_ = (NH) * 2 + n_;                                                 \
            int r_  = wn * 64 + nt_ * 16 + cn;                                       \
            int ch_ = ((kk_ << 2) | quad) ^ (r_ & 7);                                \
            bf[nt_ * 2 + kk_] = *(const f16x8*)&lB[BUF][r_ * BK + ch_ * 8];          \
        }                                                                            \
} while (0)

#define QUAD_MFMA(MH, NH) do {                                                       \
    __builtin_amdgcn_s_setprio(1);                                                   \
    _Pragma("unroll")                                                                \
    for (int m_ = 0; m_ < 2; ++m_)                                                   \
        _Pragma("unroll")                                                            \
        for (int n_ = 0; n_ < 2; ++n_) {                                             \
            _Pragma("unroll")                                                        \
            for (int kk_ = 0; kk_ < 2; ++kk_)                                        \
                acc[(MH) * 2 + m_][(NH) * 2 + n_] =                                  \
                    __builtin_amdgcn_mfma_f32_16x16x32_f16(                          \
                        af[m_ * 2 + kk_], bf[((NH) * 2 + n_) * 2 + kk_],             \
                        acc[(MH) * 2 + m_][(NH) * 2 + n_], 0, 0, 0);                 \
        }                                                                            \
    __builtin_amdgcn_s_setprio(0);                                                   \
} while (0)

    const int ntile = K / BK;
    STAGE(0, 0);
    __syncthreads();
    int bufc = 0;
    for (int t = 0; t < ntile; ++t) {
        const int k0 = t * BK;
        // ---- phase 0: quadrant (0,0); prefetch entire next K-tile
        LDA_FRAGS(bufc, 0);
        LDB_FRAGS(bufc, 0);
        if (t + 1 < ntile) STAGE(bufc ^ 1, k0 + BK);
        __builtin_amdgcn_s_barrier();
        QUAD_MFMA(0, 0);
        __builtin_amdgcn_s_barrier();
        // ---- phase 1: quadrant (0,1)
        LDB_FRAGS(bufc, 1);
        __builtin_amdgcn_s_barrier();
        QUAD_MFMA(0, 1);
        __builtin_amdgcn_s_barrier();
        // ---- phase 2: quadrant (1,1)
        LDA_FRAGS(bufc, 1);
        __builtin_amdgcn_s_barrier();
        QUAD_MFMA(1, 1);
        __builtin_amdgcn_s_barrier();
        // ---- phase 3: quadrant (1,0) — all frags resident
        QUAD_MFMA(1, 0);
        __syncthreads();   // drains vmcnt(0)+lgkmcnt(0); prefetch landed long ago
        bufc ^= 1;
    }

#undef STAGE
#undef LDA_FRAGS
#undef LDB_FRAGS
#undef QUAD_MFMA

    // C/D layout: col = lane&15, row = quad*4 + reg
    if constexpr (MODE == MODE_PROJ) {
        if (z < 2) {
            f16* O = (f16*)O0 + (long)z * BIGN;   // qp / kp
            #pragma unroll
            for (int mt = 0; mt < 4; ++mt) {
                int r0 = row0 + wm * 64 + mt * 16 + quad * 4;
                #pragma unroll
                for (int nt = 0; nt < 4; ++nt) {
                    int c = col0 + wn * 64 + nt * 16 + cn;
                    #pragma unroll
                    for (int reg = 0; reg < 4; ++reg)
                        O[(size_t)(r0 + reg) * DK + c] = (f16)acc[mt][nt][reg];
                }
            }
        } else {
            // v: transposed store -> vpT[b][e][s]
            #pragma unroll
            for (int mt = 0; mt < 4; ++mt) {
                int r0 = row0 + wm * 64 + mt * 16 + quad * 4;
                int b  = r0 >> 11;
                int s  = r0 & 2047;
                f16* O = (f16*)O1 + (long)b * SD;
                #pragma unroll
                for (int nt = 0; nt < 4; ++nt) {
                    int c = col0 + wn * 64 + nt * 16 + cn;
                    f16x4 h = {(f16)acc[mt][nt][0], (f16)acc[mt][nt][1],
                               (f16)acc[mt][nt][2], (f16)acc[mt][nt][3]};
                    *(f16x4*)&O[(size_t)c * S + s] = h;
                }
            }
        }
    } else if constexpr (MODE == MODE_SCORES) {
        f16* O = (f16*)O0 + (long)z * SS;
        const float sl2e = 0.03125f * 1.44269504f;  // (1/32)*log2(e)
        float rs[4][4];
        #pragma unroll
        for (int mt = 0; mt < 4; ++mt)
            #pragma unroll
            for (int reg = 0; reg < 4; ++reg) rs[mt][reg] = 0.f;
        #pragma unroll
        for (int mt = 0; mt < 4; ++mt) {
            int r0 = row0 + wm * 64 + mt * 16 + quad * 4;
            #pragma unroll
            for (int nt = 0; nt < 4; ++nt) {
                int c = col0 + wn * 64 + nt * 16 + cn;
                #pragma unroll
                for (int reg = 0; reg < 4; ++reg) {
                    float vv = exp2f(acc[mt][nt][reg] * sl2e);
                    rs[mt][reg] += vv;
                    O[(size_t)(r0 + reg) * ldo + c] = (f16)vv;
                }
            }
        }
        #pragma unroll
        for (int mt = 0; mt < 4; ++mt) {
            int r0 = row0 + wm * 64 + mt * 16 + quad * 4;
            #pragma unroll
            for (int reg = 0; reg < 4; ++reg) {
                float vv = rs[mt][reg];
                vv += __shfl_xor(vv, 1);
                vv += __shfl_xor(vv, 2);
                vv += __shfl_xor(vv, 4);
                vv += __shfl_xor(vv, 8);
                if (cn == 0) atomicAdd(&rowsum[r0 + reg], vv);
            }
        }
    } else {  // MODE_PV
        float* O = (float*)O0 + (long)z * SD;
        #pragma unroll
        for (int mt = 0; mt < 4; ++mt) {
            int r0 = row0 + wm * 64 + mt * 16 + quad * 4;
            fx4 rsv = *(const fx4*)&rowsum[r0];
            fx4 inv = {1.f / rsv[0], 1.f / rsv[1], 1.f / rsv[2], 1.f / rsv[3]};
            #pragma unroll
            for (int nt = 0; nt < 4; ++nt) {
                int c = col0 + wn * 64 + nt * 16 + cn;
                #pragma unroll
                for (int reg = 0; reg < 4; ++reg)
                    O[(size_t)(r0 + reg) * ldo + c] = acc[mt][nt][reg] * inv[reg];
            }
        }
    }
}

extern "C" void kernel_launch(void* const* d_in, const int* in_sizes, int n_in,
                              void* d_out, int out_size, void* d_ws, size_t ws_size,
                              hipStream_t stream) {
    const float* q  = (const float*)d_in[0];
    const float* k  = (const float*)d_in[1];
    const float* v  = (const float*)d_in[2];
    const float* wq = (const float*)d_in[3];
    const float* wk = (const float*)d_in[4];
    const float* wv = (const float*)d_in[5];
    float* out = (float*)d_out;

    char* ws = (char*)d_ws;
    f16*   qp     = (f16*)(ws);                          // 16 MB [8192, 1024]
    f16*   kp     = (f16*)(ws + ((size_t)16 << 20));     // 16 MB [8192, 1024]
    f16*   vpT    = (f16*)(ws + ((size_t)32 << 20));     // 16 MB [B][DK][S]
    f16*   E      = (f16*)(ws + ((size_t)48 << 20));     // 32 MB [B][S][S]
    float* rowsum = (float*)(ws + ((size_t)80 << 20));   // 32 KB [B][S]

    hipMemsetAsync(rowsum, 0, (size_t)Bsz * S * sizeof(float), stream);

    convert_kernel<<<13824, 256, 0, stream>>>(q, k, v, wq, wk, wv);

    const f16* qh  = (const f16*)q;
    const f16* kh  = (const f16*)k;
    const f16* vh  = (const f16*)v;
    const f16* wqh = (const f16*)wq;
    const f16* wkh = (const f16*)wk;
    const f16* wvh = (const f16*)wv;

    dim3 blk(512);
    // fused projections: y=0 -> qp, y=1 -> kp, y=2 -> vpT (transposed)
    // 64x4 tiles -> 256 blocks/z, 768 total = 3 exact CU rounds
    gemm_kernel<MODE_PROJ><<<dim3(256, 3), blk, 0, stream>>>(
        qh, kh, vh, wqh, wkh, wvh, qp, vpT, nullptr, DK, DK, DK, DK);
    // scores: E = exp(qp.kp/32), rowsum accumulated; 16x8 tiles x4 = 512 blocks
    gemm_kernel<MODE_SCORES><<<dim3(128, 4), blk, 0, stream>>>(
        qp, nullptr, nullptr, kp, nullptr, nullptr, E, nullptr, rowsum,
        DK, DK, DK, S);
    // PV: out = (E @ vpT^T) / rowsum; 16x4 tiles x4 = 256 blocks
    gemm_kernel<MODE_PV><<<dim3(64, 4), blk, 0, stream>>>(
        E, nullptr, nullptr, vpT, nullptr, nullptr, out, nullptr, rowsum,
        S, S, S, DK);
}